// Round 7
// baseline (192.331 us; speedup 1.0000x reference)
//
#include <hip/hip_runtime.h>
#include <math.h>

// Tropical (max-plus) depthwise 3x3 conv, stride=1, pad=1, dil=1.
// x: (8,64,224,224) fp32; kernel: (64,1,3,3) fp32; out same shape.
// R6 = R5 with the LDS-pointer-array compile error fixed (buffer pointer
// computed from parity each use; no static initializer of addrspacecast).
//  - LDS staging via async global_load_lds (no dest VGPR -> unSerializable).
//  - Double-buffered tiles, 7 consecutive tiles per block: copy(n+1) issued
//    before compute(n) so the end-of-iter barrier drain overlaps compute.
//  - Compute: per thread a float4-column x 4-row strip; per input row THREE
//    shifted ds_read_b128 (conflict-free 16B-stride; R4's b32 halo reads were
//    8-way conflicted: 3.6M conflict cycles) + factored horizontal max-plus
//    (hk0/hk1/hk2) with rolling state -> 4.5 LDS ops per output float4.

#define H_DIM 224
#define W_DIM 224
#define W4 56
#define STRIP 16               // output rows per tile
#define TILES_PER_PLANE 14
#define C_DIM 64
#define NTILES (8 * C_DIM * TILES_PER_PLANE)   // 7168
#define TPB 7                  // tiles per block
#define NBLK (NTILES / TPB)    // 1024 -> exactly 4 blocks/CU
#define NEG (-INFINITY)

#define LROWS 18
#define LDW (LROWS * W_DIM)    // 4032 dwords
#define LSTRIDE (LDW + 8)      // +4 front pad, +4 back pad (16B-aligned bufs)

typedef float f4 __attribute__((ext_vector_type(4)));
typedef __attribute__((address_space(3))) void       lds_void;
typedef __attribute__((address_space(1))) const void gbl_void;

__device__ __forceinline__ void async16(const float* g, float* l) {
    __builtin_amdgcn_global_load_lds((gbl_void*)g, (lds_void*)l, 16, 0, 0);
}
__device__ __forceinline__ float m3(float a, float b, float c) {
    return fmaxf(fmaxf(a, b), c);   // -> v_max3_f32
}

__global__ __launch_bounds__(256) void tropical_conv_kernel(
    const float* __restrict__ x,
    const float* __restrict__ kw,
    float* __restrict__ out)
{
    __shared__ __align__(16) float lds_raw[2][LSTRIDE];

    int tid   = threadIdx.x;
    int tile0 = blockIdx.x * TPB;

    // ---- async tile copy: input rows [g*16-1, g*16+17) -> LDS rows [0,18) ----
    auto issue_copy = [&](int tile, int parity) {
        float* buf = &lds_raw[parity][4];
        int g  = tile % TILES_PER_PLANE;
        int bc = tile / TILES_PER_PLANE;
        const float* plane = x + (size_t)bc * (H_DIM * W_DIM);
        int r0 = g * STRIP - 1, nrows = LROWS, off = 0;
        if (g == 0)                        { r0 = 0; nrows = 17; off = W_DIM; }
        else if (g == TILES_PER_PLANE - 1) { nrows = 17; }
        const float* gsrc = plane + (size_t)r0 * W_DIM;   // contiguous stream
        int nchunk = nrows * (W_DIM / 4);
        for (int k = tid; k < nchunk; k += 256)
            async16(gsrc + k * 4, buf + off + k * 4);
        if (g == 0)                        { if (tid < W_DIM) buf[tid] = NEG; }
        else if (g == TILES_PER_PLANE - 1) { if (tid < W_DIM) buf[(LROWS - 1) * W_DIM + tid] = NEG; }
    };

    issue_copy(tile0, 0);
    __syncthreads();

    int s  = tid / W4;          // row-strip 0..3 (tid<224 active)
    int cc = tid % W4;          // float4 column
    bool active = (tid < 224);
    bool hl = (cc > 0), hr = (cc < W4 - 1);

    for (int it = 0; it < TPB; ++it) {
        int tile = tile0 + it;
        float* cur = &lds_raw[it & 1][4];
        if (it + 1 < TPB) issue_copy(tile + 1, (it + 1) & 1);

        int g  = tile % TILES_PER_PLANE;
        int bc = tile / TILES_PER_PLANE;
        int c  = bc & (C_DIM - 1);
        const float* kc = kw + c * 9;
        float k00 = kc[0], k01 = kc[1], k02 = kc[2];
        float k10 = kc[3], k11 = kc[4], k12 = kc[5];
        float k20 = kc[6], k21 = kc[7], k22 = kc[8];
        float* orow0 = out + (size_t)bc * (H_DIM * W_DIM)
                           + (size_t)(g * STRIP + s * 4) * W_DIM + cc * 4;

        if (active) {
            f4 hk0_2, hk0_1, hk1_1;
            #pragma unroll
            for (int j = 0; j < 6; ++j) {
                int a = (s * 4 + j) * W_DIM + cc * 4;   // LDS dword index
                f4 A = *(const f4*)&cur[a - 4];
                f4 B = *(const f4*)&cur[a];
                f4 C = *(const f4*)&cur[a + 4];
                float w0 = hl ? A.w : NEG;
                float w1 = B.x, w2 = B.y, w3 = B.z, w4 = B.w;
                float w5 = hr ? C.x : NEG;

                f4 hk0, hk1, hk2;
                if (j <= 3) {                      // used at j+2
                    hk0.x = m3(w0 + k00, w1 + k01, w2 + k02);
                    hk0.y = m3(w1 + k00, w2 + k01, w3 + k02);
                    hk0.z = m3(w2 + k00, w3 + k01, w4 + k02);
                    hk0.w = m3(w3 + k00, w4 + k01, w5 + k02);
                }
                if (j >= 1 && j <= 4) {            // used at j+1
                    hk1.x = m3(w0 + k10, w1 + k11, w2 + k12);
                    hk1.y = m3(w1 + k10, w2 + k11, w3 + k12);
                    hk1.z = m3(w2 + k10, w3 + k11, w4 + k12);
                    hk1.w = m3(w3 + k10, w4 + k11, w5 + k12);
                }
                if (j >= 2) {                      // used now
                    hk2.x = m3(w0 + k20, w1 + k21, w2 + k22);
                    hk2.y = m3(w1 + k20, w2 + k21, w3 + k22);
                    hk2.z = m3(w2 + k20, w3 + k21, w4 + k22);
                    hk2.w = m3(w3 + k20, w4 + k21, w5 + k22);

                    f4 o;
                    o.x = m3(hk0_2.x, hk1_1.x, hk2.x);
                    o.y = m3(hk0_2.y, hk1_1.y, hk2.y);
                    o.z = m3(hk0_2.z, hk1_1.z, hk2.z);
                    o.w = m3(hk0_2.w, hk1_1.w, hk2.w);
                    *(f4*)(orow0 + (size_t)(j - 2) * W_DIM) = o;
                }
                hk0_2 = hk0_1; hk0_1 = hk0; hk1_1 = hk1;
            }
        }
        __syncthreads();   // drains copy(n+1) [overlapped with compute above]
                           // and fences buffer reuse
    }
}

extern "C" void kernel_launch(void* const* d_in, const int* in_sizes, int n_in,
                              void* d_out, int out_size, void* d_ws, size_t ws_size,
                              hipStream_t stream) {
    const float* x    = (const float*)d_in[0];
    const float* kern = (const float*)d_in[1];
    float* out        = (float*)d_out;

    tropical_conv_kernel<<<NBLK, 256, 0, stream>>>(x, kern, out);
}